// Round 6
// baseline (318.588 us; speedup 1.0000x reference)
//
#include <hip/hip_runtime.h>
#include <hip/hip_bf16.h>
#include <stdint.h>

// Problem constants
#define BSZ 256
#define NQ 4096          // Q_SIZE
#define N1 8320          // GEMM1 padded N: [qkv_half 4096 | gate 4096 | alpha 32 | beta 32 | pad 64]
#define K1 2048
#define N3 2048
#define K3 4096
#define Z3 4             // gemm3 split-K slabs
#define LP 20            // LDS padded row stride (floats): <=2-way banks in all phases

typedef __attribute__((ext_vector_type(8))) short bf16x8;
typedef __attribute__((ext_vector_type(4))) float f32x4;

__device__ __forceinline__ unsigned short f2bf(float f) {
  union { float f; unsigned u; } v; v.f = f;
  unsigned r = v.u + 0x7fffu + ((v.u >> 16) & 1u);   // RNE
  return (unsigned short)(r >> 16);
}

// fp32x8 -> bf16x8 via v_cvt_pk_bf16_f32 (RNE, same numerics as f2bf)
__device__ __forceinline__ bf16x8 pack8(float4 a, float4 b) {
  union { bf16x8 v; __hip_bfloat162 h[4]; } o;
  o.h[0] = __float22bfloat162_rn(float2{a.x, a.y});
  o.h[1] = __float22bfloat162_rn(float2{a.z, a.w});
  o.h[2] = __float22bfloat162_rn(float2{b.x, b.y});
  o.h[3] = __float22bfloat162_rn(float2{b.z, b.w});
  return o.v;
}

// ---------------- K0: hidden fp32 -> bf16 ----------------
__global__ __launch_bounds__(256) void cvt_kernel(const float* __restrict__ x,
                                                  unsigned short* __restrict__ y) {
  int i = (blockIdx.x * 256 + threadIdx.x) * 8;
  float4 a = *(const float4*)(x + i);
  float4 b = *(const float4*)(x + i + 4);
  ushort4 o0 = { f2bf(a.x), f2bf(a.y), f2bf(a.z), f2bf(a.w) };
  ushort4 o1 = { f2bf(b.x), f2bf(b.y), f2bf(b.z), f2bf(b.w) };
  *(ushort4*)(y + i) = o0;
  *(ushort4*)(y + i + 4) = o1;
}

// ================= GEMM core: 16-col full-M waves, in-block split-K x4 ========
// Block (256 thr, 4 waves) owns 16 output cols x all M=256 rows -> each B row
// read by exactly ONE block (unique-B). Wave w takes a K-chunk; partials merge
// through a 2-buffer LDS tree (41 KB). Small acc tile (16 f32x4 = 64 VGPR)
// leaves the compiler room to pipeline; explicit depth-2 B prefetch rotation
// covers HBM latency. No DMA engine, no counted vmcnt: pure reg streaming,
// the only structure that delivered >2.5 TB/s in rounds 0-5 (round 3).
// MFMA 16x16x32 mapping (numerically verified rounds 3-5):
//   A-frag lane l: A[i*16 + (l&15)][kk + 8*(l>>4) .. +8]
//   B-frag lane l: B[n0 + (l&15)][kk + 8*(l>>4) .. +8] (fp32 -> cvt_pk bf16)
//   C lane l reg r: C[i*16 + (l>>4)*4 + r][n0 + (l&15)]

// ---------------- K1: GEMM1  P = hidden @ [Wqkv_half;Wgate;Walpha;Wbeta]^T ----------------
// 516 blocks; block b: cols b*16..+15 (beta ends at block 515; no pad blocks).
// wave w: K [w*512, +512) = 16 steps.
__global__ __launch_bounds__(256) void gemm1_kernel(
    const unsigned short* __restrict__ A16,   // [256][2048] bf16
    const float* __restrict__ Wqkv, const float* __restrict__ Wgate,
    const float* __restrict__ Walpha, const float* __restrict__ Wbeta,
    float* __restrict__ P) {                  // [256][8320] fp32
  __shared__ float lds[2][256 * LP];          // 40,960 B
  const int tid = threadIdx.x, lane = tid & 63, wv = tid >> 6;
  const int l15 = lane & 15, q = lane >> 4, hi8 = q * 8;
  const int n0 = blockIdx.x * 16;
  const int k0 = wv * 512;

  const int ng = n0 + l15;
  const float* Brow;
  if (ng < 4096)       Brow = Wqkv  + (size_t)(4096 + ng) * K1;
  else if (ng < 8192)  Brow = Wgate + (size_t)(ng - 4096) * K1;
  else if (ng < 8224)  Brow = Walpha + (size_t)(ng - 8192) * K1;
  else                 Brow = Wbeta + (size_t)(ng - 8224) * K1;
  Brow += hi8;
  const unsigned short* Arow = A16 + (size_t)l15 * K1 + hi8;

  f32x4 acc[16];
#pragma unroll
  for (int i = 0; i < 16; i++) { f32x4 z = {0.f, 0.f, 0.f, 0.f}; acc[i] = z; }

  // depth-2 rotating B prefetch
  float4 b0a = *(const float4*)(Brow + k0);
  float4 b0b = *(const float4*)(Brow + k0 + 4);
  float4 b1a = *(const float4*)(Brow + k0 + 32);
  float4 b1b = *(const float4*)(Brow + k0 + 36);
#pragma unroll 2
  for (int s = 0; s < 16; s++) {
    const int kk = k0 + s * 32;
    bf16x8 bF = pack8(b0a, b0b);
    b0a = b1a; b0b = b1b;
    if (s < 14) {
      b1a = *(const float4*)(Brow + kk + 64);
      b1b = *(const float4*)(Brow + kk + 68);
    }
#pragma unroll
    for (int i = 0; i < 16; i++) {
      bf16x8 aF = *(const bf16x8*)(Arow + (size_t)i * 16 * K1 + kk);
      acc[i] = __builtin_amdgcn_mfma_f32_16x16x32_bf16(aF, bF, acc[i], 0, 0, 0);
    }
  }

  // --- 4-partial LDS tree reduce (2 buffers), then store ---
  if (wv < 2) {
    float* buf = lds[wv];
#pragma unroll
    for (int i = 0; i < 16; i++)
#pragma unroll
      for (int r = 0; r < 4; r++)
        buf[(i * 16 + q * 4 + r) * LP + l15] = acc[i][r];
  }
  __syncthreads();
  if (wv >= 2) {
    float* buf = lds[wv - 2];
#pragma unroll
    for (int i = 0; i < 16; i++)
#pragma unroll
      for (int r = 0; r < 4; r++)
        buf[(i * 16 + q * 4 + r) * LP + l15] += acc[i][r];
  }
  __syncthreads();
#pragma unroll
  for (int j = 0; j < 16; j++) {
    int row = wv * 64 + q + 4 * j;
    float v = lds[0][row * LP + l15] + lds[1][row * LP + l15];
    P[(size_t)row * N1 + n0 + l15] = v;
  }
}

// ---------------- K2: per-row fused conv + SSM + RMS + gate; writes core bf16 ----------------
__global__ __launch_bounds__(512) void fuse_kernel(
    const float* __restrict__ P,        // [256][8320]
    const float* __restrict__ bqkv,     // [8192]
    const float* __restrict__ ck,       // [8192][4]
    const float* __restrict__ cstate,   // [256][4][8192]
    const float* __restrict__ ssa,      // [32]
    const float* __restrict__ dtb,      // [32]
    const float* __restrict__ nw,       // [128]
    const float* __restrict__ sstate,   // [256][32]
    unsigned short* __restrict__ C16) { // [256][4096] bf16
  __shared__ __align__(16) float cb[4096];
  __shared__ float gsum[64];
  __shared__ float ssl[32];
  __shared__ float red[16];
  const int b = blockIdx.x, tid = threadIdx.x;
  const int lane = tid & 63, wv = tid >> 6;
  const float* P0 = P + (size_t)b * N1;

  if (wv == 0) {   // mean(ssm_norm_weight)
    float m = nw[lane] + nw[lane + 64];
#pragma unroll
    for (int off = 32; off; off >>= 1) m += __shfl_down(m, off, 64);
    if (lane == 0) red[8] = m * (1.f / 128.f);
  }

  // pass 1: core_base (conv) + group sums via 16-lane shuffle reduce
#pragma unroll
  for (int it = 0; it < 2; it++) {
    int j = (it * 512 + tid) * 4;
    float4 q0 = *(const float4*)(P0 + j);
    float4 bq = *(const float4*)(bqkv + NQ + j);
    float mqx = q0.x + bq.x, mqy = q0.y + bq.y;
    float mqz = q0.z + bq.z, mqw = q0.w + bq.w;
    const float* csb = cstate + (size_t)b * 4 * 8192 + NQ + j;
    float4 c1 = *(const float4*)(csb + 8192);
    float4 c2 = *(const float4*)(csb + 16384);
    float4 c3 = *(const float4*)(csb + 24576);
    float4 k0v = *(const float4*)(ck + (size_t)(NQ + j) * 4);
    float4 k1v = *(const float4*)(ck + (size_t)(NQ + j + 1) * 4);
    float4 k2v = *(const float4*)(ck + (size_t)(NQ + j + 2) * 4);
    float4 k3v = *(const float4*)(ck + (size_t)(NQ + j + 3) * 4);
    float4 cbv;
    cbv.x = c1.x * k0v.x + c2.x * k0v.y + c3.x * k0v.z + mqx * k0v.w;
    cbv.y = c1.y * k1v.x + c2.y * k1v.y + c3.y * k1v.z + mqy * k1v.w;
    cbv.z = c1.z * k2v.x + c2.z * k2v.y + c3.z * k2v.z + mqz * k2v.w;
    cbv.w = c1.w * k3v.x + c2.w * k3v.y + c3.w * k3v.z + mqw * k3v.w;
    *(float4*)(cb + j) = cbv;
    float s = cbv.x + cbv.y + cbv.z + cbv.w;
    s += __shfl_xor(s, 1, 64); s += __shfl_xor(s, 2, 64);
    s += __shfl_xor(s, 4, 64); s += __shfl_xor(s, 8, 64);
    if ((lane & 15) == 0) gsum[(it * 512 + tid) >> 4] = s;
  }
  __syncthreads();

  if (tid < 32) {
    float a  = P0[8192 + tid];
    float bc = P0[8224 + tid];
    float kg = gsum[tid] * (1.f / 64.f);
    float vg = gsum[32 + tid] * (1.f / 64.f);
    float x = a + dtb[tid];
    float sp = fmaxf(x, 0.f) + log1pf(expf(-fabsf(x)));   // stable softplus
    float g = -expf(ssa[tid]) * sp;
    float beta = 1.f / (1.f + expf(-bc));
    float ns = expf(g) * sstate[b * 32 + tid] + beta * vg;
    ssl[tid] = ns / (1.f + expf(-kg));
  }
  __syncthreads();

  // pass 2: core1 = core_base + expanded; sum of squares
  float sq = 0.f;
  float4 c1r[2];
#pragma unroll
  for (int it = 0; it < 2; it++) {
    int j = (it * 512 + tid) * 4;
    float4 v = *(const float4*)(cb + j);
    float sv = ssl[j >> 7];
    v.x += sv; v.y += sv; v.z += sv; v.w += sv;
    c1r[it] = v;
    sq += v.x * v.x + v.y * v.y + v.z * v.z + v.w * v.w;
  }
#pragma unroll
  for (int off = 32; off; off >>= 1) sq += __shfl_down(sq, off, 64);
  if (lane == 0) red[wv] = sq;
  __syncthreads();
  if (tid == 0) {
    float t = red[0] + red[1] + red[2] + red[3] + red[4] + red[5] + red[6] + red[7];
    red[9] = rsqrtf(t * (1.f / 4096.f) + 1e-6f);
  }
  __syncthreads();
  float rms = red[9], mwv = red[8];

  // pass 3: apply gate, write bf16
#pragma unroll
  for (int it = 0; it < 2; it++) {
    int j = (it * 512 + tid) * 4;
    float4 g0x = *(const float4*)(P0 + NQ + j);
    float4 v = c1r[it];
    float ox = v.x * rms * mwv / (1.f + expf(-g0x.x));
    float oy = v.y * rms * mwv / (1.f + expf(-g0x.y));
    float oz = v.z * rms * mwv / (1.f + expf(-g0x.z));
    float ow = v.w * rms * mwv / (1.f + expf(-g0x.w));
    ushort4 u = { f2bf(ox), f2bf(oy), f2bf(oz), f2bf(ow) };
    *(ushort4*)(C16 + (size_t)b * 4096 + j) = u;
  }
}

// ---------------- K3: GEMM3 OP[z] = core @ Wout^T ----------------
// 512 blocks = (z 0..3) x (n 0..127); block: 16 cols, K-slab z*1024..+1024;
// wave w: K-chunk 256 = 8 steps. Same LDS tree reduce; writes OP slab z.
__global__ __launch_bounds__(256) void gemm3_kernel(
    const unsigned short* __restrict__ A16,  // core [256][4096] bf16
    const float* __restrict__ Wout,          // [2048][4096] fp32
    float* __restrict__ OP) {                // [4][256][2048] fp32 slabs
  __shared__ float lds[2][256 * LP];
  const int tid = threadIdx.x, lane = tid & 63, wv = tid >> 6;
  const int l15 = lane & 15, q = lane >> 4, hi8 = q * 8;
  const int z = blockIdx.x >> 7;
  const int n0 = (blockIdx.x & 127) * 16;
  const int k0 = z * 1024 + wv * 256;

  const float* Brow = Wout + (size_t)(n0 + l15) * K3 + hi8;
  const unsigned short* Arow = A16 + (size_t)l15 * K3 + hi8;

  f32x4 acc[16];
#pragma unroll
  for (int i = 0; i < 16; i++) { f32x4 zz = {0.f, 0.f, 0.f, 0.f}; acc[i] = zz; }

  float4 b0a = *(const float4*)(Brow + k0);
  float4 b0b = *(const float4*)(Brow + k0 + 4);
  float4 b1a = *(const float4*)(Brow + k0 + 32);
  float4 b1b = *(const float4*)(Brow + k0 + 36);
#pragma unroll 2
  for (int s = 0; s < 8; s++) {
    const int kk = k0 + s * 32;
    bf16x8 bF = pack8(b0a, b0b);
    b0a = b1a; b0b = b1b;
    if (s < 6) {
      b1a = *(const float4*)(Brow + kk + 64);
      b1b = *(const float4*)(Brow + kk + 68);
    }
#pragma unroll
    for (int i = 0; i < 16; i++) {
      bf16x8 aF = *(const bf16x8*)(Arow + (size_t)i * 16 * K3 + kk);
      acc[i] = __builtin_amdgcn_mfma_f32_16x16x32_bf16(aF, bF, acc[i], 0, 0, 0);
    }
  }

  if (wv < 2) {
    float* buf = lds[wv];
#pragma unroll
    for (int i = 0; i < 16; i++)
#pragma unroll
      for (int r = 0; r < 4; r++)
        buf[(i * 16 + q * 4 + r) * LP + l15] = acc[i][r];
  }
  __syncthreads();
  if (wv >= 2) {
    float* buf = lds[wv - 2];
#pragma unroll
    for (int i = 0; i < 16; i++)
#pragma unroll
      for (int r = 0; r < 4; r++)
        buf[(i * 16 + q * 4 + r) * LP + l15] += acc[i][r];
  }
  __syncthreads();
  float* Oz = OP + (size_t)z * ((size_t)BSZ * N3);
#pragma unroll
  for (int j = 0; j < 16; j++) {
    int row = wv * 64 + q + 4 * j;
    float v = lds[0][row * LP + l15] + lds[1][row * LP + l15];
    Oz[(size_t)row * N3 + n0 + l15] = v;
  }
}

// ---------------- K4: reduce 4 slabs -> out ----------------
__global__ __launch_bounds__(256) void reduce_kernel(const float* __restrict__ OP,
                                                     float* __restrict__ out) {
  int i = (blockIdx.x * 256 + threadIdx.x) * 4;
  float4 s = *(const float4*)(OP + i);
#pragma unroll
  for (int z = 1; z < Z3; z++) {
    float4 v = *(const float4*)(OP + (size_t)z * BSZ * N3 + i);
    s.x += v.x; s.y += v.y; s.z += v.z; s.w += v.w;
  }
  *(float4*)(out + i) = s;
}

extern "C" void kernel_launch(void* const* d_in, const int* in_sizes, int n_in,
                              void* d_out, int out_size, void* d_ws, size_t ws_size,
                              hipStream_t stream) {
  const float* hidden = (const float*)d_in[0];
  const float* Wqkv   = (const float*)d_in[1];
  const float* bqkv   = (const float*)d_in[2];
  const float* Wgate  = (const float*)d_in[3];
  const float* Walpha = (const float*)d_in[4];
  const float* Wbeta  = (const float*)d_in[5];
  const float* Wout   = (const float*)d_in[6];
  const float* ssa    = (const float*)d_in[7];
  const float* dtb    = (const float*)d_in[8];
  const float* nw     = (const float*)d_in[9];
  const float* ck     = (const float*)d_in[10];
  const float* sstate = (const float*)d_in[11];
  const float* cstate = (const float*)d_in[12];
  float* out = (float*)d_out;

  char* ws = (char*)d_ws;
  unsigned short* A16 = (unsigned short*)ws;                          // 1 MB
  float* P   = (float*)(ws + (1 << 20));                              // 256*8320*4 = 8,519,680 B
  unsigned short* C16 = (unsigned short*)(ws + (1 << 20) + 8519680);  // 2 MB
  float* OP  = (float*)(ws + (1 << 20) + 8519680 + (2 << 20));        // 4*256*2048*4 = 8 MB

  cvt_kernel<<<256, 256, 0, stream>>>(hidden, A16);
  gemm1_kernel<<<516, 256, 0, stream>>>(A16, Wqkv, Wgate, Walpha, Wbeta, P);
  fuse_kernel<<<256, 512, 0, stream>>>(P, bqkv, ck, cstate, ssa, dtb, nw, sstate, C16);
  gemm3_kernel<<<512, 256, 0, stream>>>(C16, Wout, OP);
  reduce_kernel<<<512, 256, 0, stream>>>(OP, out);
}

// Round 7
// 217.054 us; speedup vs baseline: 1.4678x; 1.4678x over previous
//
#include <hip/hip_runtime.h>
#include <hip/hip_bf16.h>
#include <stdint.h>

// Problem constants
#define BSZ 256
#define NQ 4096
#define K1 2048
#define N3 2048
#define K3 4096
#define Z1 4                      // gemm1 K-split (P slabs)
#define Z3 8                      // gemm3 K-split (OP slabs)
#define ZAB 32                    // alpha/beta K-split (Pab slabs)
#define PSTR ((size_t)BSZ * 8192) // P slab stride (floats)

typedef __attribute__((ext_vector_type(8))) short bf16x8;
typedef __attribute__((ext_vector_type(4))) float f32x4;

__device__ __forceinline__ unsigned short f2bf(float f) {
  union { float f; unsigned u; } v; v.f = f;
  unsigned r = v.u + 0x7fffu + ((v.u >> 16) & 1u);   // RNE
  return (unsigned short)(r >> 16);
}

__device__ __forceinline__ bf16x8 pack8(float4 a, float4 b) {
  union { bf16x8 v; __hip_bfloat162 h[4]; } o;
  o.h[0] = __float22bfloat162_rn(float2{a.x, a.y});
  o.h[1] = __float22bfloat162_rn(float2{a.z, a.w});
  o.h[2] = __float22bfloat162_rn(float2{b.x, b.y});
  o.h[3] = __float22bfloat162_rn(float2{b.z, b.w});
  return o.v;
}

__device__ __forceinline__ void gload_lds16(const void* g, void* lds_uniform) {
  __builtin_amdgcn_global_load_lds(
      (const __attribute__((address_space(1))) unsigned int*)g,
      (__attribute__((address_space(3))) unsigned int*)lds_uniform, 16, 0, 0);
}

// ---------------- K0: hidden fp32 -> bf16 ----------------
__global__ __launch_bounds__(256) void cvt_kernel(const float* __restrict__ x,
                                                  unsigned short* __restrict__ y) {
  int i = (blockIdx.x * 256 + threadIdx.x) * 8;
  float4 a = *(const float4*)(x + i);
  float4 b = *(const float4*)(x + i + 4);
  ushort4 o0 = { f2bf(a.x), f2bf(a.y), f2bf(a.z), f2bf(a.w) };
  ushort4 o1 = { f2bf(b.x), f2bf(b.y), f2bf(b.z), f2bf(b.w) };
  *(ushort4*)(y + i) = o0;
  *(ushort4*)(y + i + 4) = o1;
}

// ================= GEMM1: full-M256 x N128 tiles, BK=64, 8 waves ==============
// Port-traffic-minimal design (see session model: ~12.8 B/cy/CU load-path cap):
//   A (bf16, 32 KB/iter) staged via global_load_lds DMA, XOR-swizzled.
//   B (fp32, 32 KB/iter) reg-staged with issue-early/write-late prefetch,
//     converted to bf16 (16 KB LDS), XOR-swizzled.
// Grid: 256 main blocks = 64 n-blocks (cols 0..8191) x Z1=4 K-slabs
//     + 32 alpha/beta blocks (64 cols x K=64 each -> Pab slabs).
// LDS layouts: row = 128 B = 8 chunks of 16 B; phys chunk = c ^ (row&7).
// MFMA fragment mapping (verified rounds 0-6):
//   A/B-frag lane l: row (l&15), k = ks*32 + 8*(l>>4) -> chunk = ks*4 + (l>>4)
//   C lane l reg r: row (l>>4)*4 + r, col (l&15)
__global__ __launch_bounds__(512) void gemm1_kernel(
    const unsigned short* __restrict__ A16,   // [256][2048] bf16
    const float* __restrict__ Wqkv, const float* __restrict__ Wgate,
    const float* __restrict__ Walpha, const float* __restrict__ Wbeta,
    float* __restrict__ P,                    // [4][256][8192] fp32 slabs
    float* __restrict__ Pab) {                // [32][256][64] fp32 slabs
  __shared__ __align__(16) unsigned short sA[256 * 64];   // 32 KB
  __shared__ __align__(16) unsigned short sB[128 * 64];   // 16 KB
  const int tid = threadIdx.x, lane = tid & 63, wv = tid >> 6;
  const int l15 = lane & 15, q4 = lane >> 4;
  const int wm = wv >> 1, wn = wv & 1;
  const int bx = blockIdx.x;

  if (bx < 256) {
    // ---------------- main path: cols 0..8191, K-slab z ----------------
    const int n0 = (bx & 63) * 128;
    const int k0 = (bx >> 6) * 512;

    // A DMA: 32 instrs (4/wave); instr s: rows 8s..8s+7, lane: row 8s+(l>>3),
    // phys chunk l&7 <- logical chunk (l&7)^((l>>3)&7)
    const char* aS[4]; char* aD[4];
#pragma unroll
    for (int t = 0; t < 4; t++) {
      int s = wv * 4 + t;
      int m = 8 * s + (lane >> 3);
      int c = (lane & 7) ^ ((lane >> 3) & 7);
      aS[t] = (const char*)(A16 + (size_t)m * K1 + k0) + c * 16;
      aD[t] = (char*)sA + s * 1024;
    }
    // B reg-staging: thread t: row r=t>>2 (0..127), quarter qq=t&3 (16 floats)
    const int r = tid >> 2, qq = tid & 3;
    const int ng = n0 + r;
    const float* Bp = (ng < 4096 ? Wqkv + (size_t)(4096 + ng) * K1
                                 : Wgate + (size_t)(ng - 4096) * K1) + k0 + qq * 16;
    char* bw0 = (char*)sB + r * 128 + (((2 * qq) ^ (r & 7)) * 16);
    char* bw1 = (char*)sB + r * 128 + (((2 * qq + 1) ^ (r & 7)) * 16);

    f32x4 acc[4][4];
#pragma unroll
    for (int i = 0; i < 4; i++)
#pragma unroll
      for (int j = 0; j < 4; j++) { f32x4 z = {0.f,0.f,0.f,0.f}; acc[i][j] = z; }

    // prologue: B(0) into regs
    float4 br0 = *(const float4*)(Bp);
    float4 br1 = *(const float4*)(Bp + 4);
    float4 br2 = *(const float4*)(Bp + 8);
    float4 br3 = *(const float4*)(Bp + 12);

    for (int it = 0; it < 8; ++it) {
      __syncthreads();                                  // LDS free; drains B prefetch
#pragma unroll
      for (int t = 0; t < 4; t++) gload_lds16(aS[t] + it * 128, aD[t]);
      *(bf16x8*)bw0 = pack8(br0, br1);                  // B(it) -> LDS bf16
      *(bf16x8*)bw1 = pack8(br2, br3);
      __syncthreads();                                  // staged (A DMA + B writes)
      if (it < 7) {                                     // issue B(it+1); lands under compute
        const float* bp = Bp + (it + 1) * 64;
        br0 = *(const float4*)(bp);
        br1 = *(const float4*)(bp + 4);
        br2 = *(const float4*)(bp + 8);
        br3 = *(const float4*)(bp + 12);
      }
#pragma unroll
      for (int ks = 0; ks < 2; ks++) {
        bf16x8 bF[4];
#pragma unroll
        for (int j = 0; j < 4; j++) {
          int row = wn * 64 + j * 16 + l15;
          bF[j] = *(const bf16x8*)((const char*)sB + row * 128 +
                                   (((ks * 4 + q4) ^ (row & 7)) * 16));
        }
#pragma unroll
        for (int i = 0; i < 4; i++) {
          int m = wm * 64 + i * 16 + l15;
          bf16x8 aF = *(const bf16x8*)((const char*)sA + m * 128 +
                                       (((ks * 4 + q4) ^ (m & 7)) * 16));
#pragma unroll
          for (int j = 0; j < 4; j++)
            acc[i][j] = __builtin_amdgcn_mfma_f32_16x16x32_bf16(aF, bF[j], acc[i][j], 0, 0, 0);
        }
      }
    }

    float* Pz = P + (size_t)(bx >> 6) * PSTR;
#pragma unroll
    for (int i = 0; i < 4; i++)
#pragma unroll
      for (int j = 0; j < 4; j++) {
        int row = wm * 64 + i * 16 + q4 * 4;
        int col = n0 + wn * 64 + j * 16 + l15;
#pragma unroll
        for (int rr = 0; rr < 4; rr++)
          Pz[(size_t)(row + rr) * 8192 + col] = acc[i][j][rr];
      }
  } else {
    // ---------------- alpha/beta path: 64 cols, K-chunk 64 ----------------
    const int iab = bx - 256;                 // 0..31
    const int kk = iab * 64;

    const char* aS[4]; char* aD[4];
#pragma unroll
    for (int t = 0; t < 4; t++) {
      int s = wv * 4 + t;
      int m = 8 * s + (lane >> 3);
      int c = (lane & 7) ^ ((lane >> 3) & 7);
      aS[t] = (const char*)(A16 + (size_t)m * K1 + kk) + c * 16;
      aD[t] = (char*)sA + s * 1024;
    }
    // B: 64 rows (alpha 0..31, beta 32..63); thread: row r=t>>3, eighth e=t&7
    const int r = tid >> 3, e = tid & 7;
    const float* Bp = (r < 32 ? Walpha + (size_t)r * K1
                              : Wbeta + (size_t)(r - 32) * K1) + kk + e * 8;
    float4 br0 = *(const float4*)(Bp);
    float4 br1 = *(const float4*)(Bp + 4);

#pragma unroll
    for (int t = 0; t < 4; t++) gload_lds16(aS[t], aD[t]);
    *(bf16x8*)((char*)sB + r * 128 + ((e ^ (r & 7)) * 16)) = pack8(br0, br1);
    __syncthreads();

    f32x4 acc[4][2];
#pragma unroll
    for (int i = 0; i < 4; i++)
#pragma unroll
      for (int j = 0; j < 2; j++) { f32x4 z = {0.f,0.f,0.f,0.f}; acc[i][j] = z; }

#pragma unroll
    for (int ks = 0; ks < 2; ks++) {
      bf16x8 bF[2];
#pragma unroll
      for (int j = 0; j < 2; j++) {
        int row = wn * 32 + j * 16 + l15;
        bF[j] = *(const bf16x8*)((const char*)sB + row * 128 +
                                 (((ks * 4 + q4) ^ (row & 7)) * 16));
      }
#pragma unroll
      for (int i = 0; i < 4; i++) {
        int m = wm * 64 + i * 16 + l15;
        bf16x8 aF = *(const bf16x8*)((const char*)sA + m * 128 +
                                     (((ks * 4 + q4) ^ (m & 7)) * 16));
#pragma unroll
        for (int j = 0; j < 2; j++)
          acc[i][j] = __builtin_amdgcn_mfma_f32_16x16x32_bf16(aF, bF[j], acc[i][j], 0, 0, 0);
      }
    }

    float* Pz = Pab + (size_t)iab * (BSZ * 64);
#pragma unroll
    for (int i = 0; i < 4; i++)
#pragma unroll
      for (int j = 0; j < 2; j++) {
        int row = wm * 64 + i * 16 + q4 * 4;
        int col = wn * 32 + j * 16 + l15;
#pragma unroll
        for (int rr = 0; rr < 4; rr++)
          Pz[(size_t)(row + rr) * 64 + col] = acc[i][j][rr];
      }
  }
}

// ---------------- K2: fused conv + SSM + RMS + gate (sums Z1 P slabs) ---------
__global__ __launch_bounds__(512) void fuse_kernel(
    const float* __restrict__ P,        // [4][256][8192]
    const float* __restrict__ Pab,      // [32][256][64]
    const float* __restrict__ bqkv,     // [8192]
    const float* __restrict__ ck,       // [8192][4]
    const float* __restrict__ cstate,   // [256][4][8192]
    const float* __restrict__ ssa,      // [32]
    const float* __restrict__ dtb,      // [32]
    const float* __restrict__ nw,       // [128]
    const float* __restrict__ sstate,   // [256][32]
    unsigned short* __restrict__ C16) { // [256][4096] bf16
  __shared__ __align__(16) float cb[4096];
  __shared__ float gsum[64];
  __shared__ float ssl[32];
  __shared__ float red[16];
  const int b = blockIdx.x, tid = threadIdx.x;
  const int lane = tid & 63, wv = tid >> 6;
  const float* P0 = P + (size_t)b * 8192;

  if (wv == 0) {   // mean(ssm_norm_weight)
    float m = nw[lane] + nw[lane + 64];
#pragma unroll
    for (int off = 32; off; off >>= 1) m += __shfl_down(m, off, 64);
    if (lane == 0) red[8] = m * (1.f / 128.f);
  }

  // pass 1: core_base (conv) + group sums
#pragma unroll
  for (int it = 0; it < 2; it++) {
    int j = (it * 512 + tid) * 4;
    float4 p0 = *(const float4*)(P0 + j);
    float4 p1 = *(const float4*)(P0 + PSTR + j);
    float4 p2 = *(const float4*)(P0 + 2 * PSTR + j);
    float4 p3 = *(const float4*)(P0 + 3 * PSTR + j);
    float4 bq = *(const float4*)(bqkv + NQ + j);
    float mqx = p0.x + p1.x + p2.x + p3.x + bq.x;
    float mqy = p0.y + p1.y + p2.y + p3.y + bq.y;
    float mqz = p0.z + p1.z + p2.z + p3.z + bq.z;
    float mqw = p0.w + p1.w + p2.w + p3.w + bq.w;
    const float* csb = cstate + (size_t)b * 4 * 8192 + NQ + j;
    float4 c1 = *(const float4*)(csb + 8192);
    float4 c2 = *(const float4*)(csb + 16384);
    float4 c3 = *(const float4*)(csb + 24576);
    float4 k0v = *(const float4*)(ck + (size_t)(NQ + j) * 4);
    float4 k1v = *(const float4*)(ck + (size_t)(NQ + j + 1) * 4);
    float4 k2v = *(const float4*)(ck + (size_t)(NQ + j + 2) * 4);
    float4 k3v = *(const float4*)(ck + (size_t)(NQ + j + 3) * 4);
    float4 cbv;
    cbv.x = c1.x * k0v.x + c2.x * k0v.y + c3.x * k0v.z + mqx * k0v.w;
    cbv.y = c1.y * k1v.x + c2.y * k1v.y + c3.y * k1v.z + mqy * k1v.w;
    cbv.z = c1.z * k2v.x + c2.z * k2v.y + c3.z * k2v.z + mqz * k2v.w;
    cbv.w = c1.w * k3v.x + c2.w * k3v.y + c3.w * k3v.z + mqw * k3v.w;
    *(float4*)(cb + j) = cbv;
    float s = cbv.x + cbv.y + cbv.z + cbv.w;
    s += __shfl_xor(s, 1, 64); s += __shfl_xor(s, 2, 64);
    s += __shfl_xor(s, 4, 64); s += __shfl_xor(s, 8, 64);
    if ((lane & 15) == 0) gsum[(it * 512 + tid) >> 4] = s;
  }
  __syncthreads();

  if (tid < 32) {
    float a = 0.f, bc = 0.f;
    const float* pa = Pab + (size_t)b * 64 + tid;
#pragma unroll
    for (int s = 0; s < ZAB; s++) {
      a  += pa[(size_t)s * (BSZ * 64)];
      bc += pa[(size_t)s * (BSZ * 64) + 32];
    }
    float kg = gsum[tid] * (1.f / 64.f);
    float vg = gsum[32 + tid] * (1.f / 64.f);
    float x = a + dtb[tid];
    float sp = fmaxf(x, 0.f) + log1pf(expf(-fabsf(x)));   // stable softplus
    float g = -expf(ssa[tid]) * sp;
    float beta = 1.f / (1.f + expf(-bc));
    float ns = expf(g) * sstate[b * 32 + tid] + beta * vg;
    ssl[tid] = ns / (1.f + expf(-kg));
  }
  __syncthreads();

  // pass 2: core1 = core_base + expanded; sum of squares
  float sq = 0.f;
  float4 c1r[2];
#pragma unroll
  for (int it = 0; it < 2; it++) {
    int j = (it * 512 + tid) * 4;
    float4 v = *(const float4*)(cb + j);
    float sv = ssl[j >> 7];
    v.x += sv; v.y += sv; v.z += sv; v.w += sv;
    c1r[it] = v;
    sq += v.x * v.x + v.y * v.y + v.z * v.z + v.w * v.w;
  }
#pragma unroll
  for (int off = 32; off; off >>= 1) sq += __shfl_down(sq, off, 64);
  if (lane == 0) red[wv] = sq;
  __syncthreads();
  if (tid == 0) {
    float t = red[0] + red[1] + red[2] + red[3] + red[4] + red[5] + red[6] + red[7];
    red[9] = rsqrtf(t * (1.f / 4096.f) + 1e-6f);
  }
  __syncthreads();
  float rms = red[9], mwv = red[8];

  // pass 3: apply gate (sum 4 slabs), write bf16
#pragma unroll
  for (int it = 0; it < 2; it++) {
    int j = (it * 512 + tid) * 4;
    float4 g0 = *(const float4*)(P0 + NQ + j);
    float4 g1 = *(const float4*)(P0 + PSTR + NQ + j);
    float4 g2 = *(const float4*)(P0 + 2 * PSTR + NQ + j);
    float4 g3 = *(const float4*)(P0 + 3 * PSTR + NQ + j);
    float gx = g0.x + g1.x + g2.x + g3.x;
    float gy = g0.y + g1.y + g2.y + g3.y;
    float gz = g0.z + g1.z + g2.z + g3.z;
    float gw = g0.w + g1.w + g2.w + g3.w;
    float4 v = c1r[it];
    float ox = v.x * rms * mwv / (1.f + expf(-gx));
    float oy = v.y * rms * mwv / (1.f + expf(-gy));
    float oz = v.z * rms * mwv / (1.f + expf(-gz));
    float ow = v.w * rms * mwv / (1.f + expf(-gw));
    ushort4 u = { f2bf(ox), f2bf(oy), f2bf(oz), f2bf(ow) };
    *(ushort4*)(C16 + (size_t)b * 4096 + j) = u;
  }
}

// ---------------- K3: GEMM3, full-M256 x N64 tiles, Z3=8 K-slabs --------------
__global__ __launch_bounds__(512) void gemm3_kernel(
    const unsigned short* __restrict__ A16,  // core [256][4096] bf16
    const float* __restrict__ Wout,          // [2048][4096] fp32
    float* __restrict__ OP) {                // [8][256][2048] fp32 slabs
  __shared__ __align__(16) unsigned short sA[256 * 64];   // 32 KB
  __shared__ __align__(16) unsigned short sB[64 * 64];    // 8 KB
  const int tid = threadIdx.x, lane = tid & 63, wv = tid >> 6;
  const int l15 = lane & 15, q4 = lane >> 4;
  const int wm = wv >> 1, wn = wv & 1;
  const int n0 = (blockIdx.x & 31) * 64;
  const int k0 = (blockIdx.x >> 5) * 512;

  const char* aS[4]; char* aD[4];
#pragma unroll
  for (int t = 0; t < 4; t++) {
    int s = wv * 4 + t;
    int m = 8 * s + (lane >> 3);
    int c = (lane & 7) ^ ((lane >> 3) & 7);
    aS[t] = (const char*)(A16 + (size_t)m * K3 + k0) + c * 16;
    aD[t] = (char*)sA + s * 1024;
  }
  const int r = tid >> 3, e = tid & 7;    // row 0..63, eighth 0..7 (8 floats)
  const float* Bp = Wout + (size_t)(n0 + r) * K3 + k0 + e * 8;
  char* bw = (char*)sB + r * 128 + ((e ^ (r & 7)) * 16);

  f32x4 acc[4][2];
#pragma unroll
  for (int i = 0; i < 4; i++)
#pragma unroll
    for (int j = 0; j < 2; j++) { f32x4 z = {0.f,0.f,0.f,0.f}; acc[i][j] = z; }

  float4 br0 = *(const float4*)(Bp);
  float4 br1 = *(const float4*)(Bp + 4);

  for (int it = 0; it < 8; ++it) {
    __syncthreads();
#pragma unroll
    for (int t = 0; t < 4; t++) gload_lds16(aS[t] + it * 128, aD[t]);
    *(bf16x8*)bw = pack8(br0, br1);
    __syncthreads();
    if (it < 7) {
      const float* bp = Bp + (it + 1) * 64;
      br0 = *(const float4*)(bp);
      br1 = *(const float4*)(bp + 4);
    }
#pragma unroll
    for (int ks = 0; ks < 2; ks++) {
      bf16x8 bF[2];
#pragma unroll
      for (int j = 0; j < 2; j++) {
        int row = wn * 32 + j * 16 + l15;
        bF[j] = *(const bf16x8*)((const char*)sB + row * 128 +
                                 (((ks * 4 + q4) ^ (row & 7)) * 16));
      }
#pragma unroll
      for (int i = 0; i < 4; i++) {
        int m = wm * 64 + i * 16 + l15;
        bf16x8 aF = *(const bf16x8*)((const char*)sA + m * 128 +
                                     (((ks * 4 + q4) ^ (m & 7)) * 16));
#pragma unroll
        for (int j = 0; j < 2; j++)
          acc[i][j] = __builtin_amdgcn_mfma_f32_16x16x32_bf16(aF, bF[j], acc[i][j], 0, 0, 0);
      }
    }
  }

  float* Oz = OP + (size_t)(blockIdx.x >> 5) * ((size_t)BSZ * N3);
#pragma unroll
  for (int i = 0; i < 4; i++)
#pragma unroll
    for (int j = 0; j < 2; j++) {
      int row = wm * 64 + i * 16 + q4 * 4;
      int col = n0 + wn * 32 + j * 16 + l15;
#pragma unroll
      for (int rr = 0; rr < 4; rr++)
        Oz[(size_t)(row + rr) * N3 + col] = acc[i][j][rr];
    }
}

// ---------------- K4: reduce 8 slabs -> out ----------------
__global__ __launch_bounds__(256) void reduce_kernel(const float* __restrict__ OP,
                                                     float* __restrict__ out) {
  int i = (blockIdx.x * 256 + threadIdx.x) * 4;
  float4 s = *(const float4*)(OP + i);
#pragma unroll
  for (int z = 1; z < Z3; z++) {
    float4 v = *(const float4*)(OP + (size_t)z * BSZ * N3 + i);
    s.x += v.x; s.y += v.y; s.z += v.z; s.w += v.w;
  }
  *(float4*)(out + i) = s;
}

extern "C" void kernel_launch(void* const* d_in, const int* in_sizes, int n_in,
                              void* d_out, int out_size, void* d_ws, size_t ws_size,
                              hipStream_t stream) {
  const float* hidden = (const float*)d_in[0];
  const float* Wqkv   = (const float*)d_in[1];
  const float* bqkv   = (const float*)d_in[2];
  const float* Wgate  = (const float*)d_in[3];
  const float* Walpha = (const float*)d_in[4];
  const float* Wbeta  = (const float*)d_in[5];
  const float* Wout   = (const float*)d_in[6];
  const float* ssa    = (const float*)d_in[7];
  const float* dtb    = (const float*)d_in[8];
  const float* nw     = (const float*)d_in[9];
  const float* ck     = (const float*)d_in[10];
  const float* sstate = (const float*)d_in[11];
  const float* cstate = (const float*)d_in[12];
  float* out = (float*)d_out;

  char* ws = (char*)d_ws;
  unsigned short* A16 = (unsigned short*)ws;                    // 1 MB
  float* P   = (float*)(ws + (1 << 20));                        // 4*256*8192*4 = 32 MB
  float* Pab = (float*)(ws + (1 << 20) + (32 << 20));           // 32*256*64*4 = 2 MB
  unsigned short* C16 = (unsigned short*)(ws + (35 << 20));     // 2 MB
  float* OP  = P;                                               // reuse P (16 MB <= 32 MB; fuse done)

  cvt_kernel<<<256, 256, 0, stream>>>(hidden, A16);
  gemm1_kernel<<<288, 512, 0, stream>>>(A16, Wqkv, Wgate, Walpha, Wbeta, P, Pab);
  fuse_kernel<<<256, 512, 0, stream>>>(P, Pab, bqkv, ck, cstate, ssa, dtb, nw, sstate, C16);
  gemm3_kernel<<<256, 512, 0, stream>>>(C16, Wout, OP);
  reduce_kernel<<<512, 256, 0, stream>>>(OP, out);
}